// Round 1
// 379.941 us; speedup vs baseline: 1.0147x; 1.0147x over previous
//
#include <hip/hip_runtime.h>
#include <hip/hip_bf16.h>

typedef __attribute__((ext_vector_type(8))) short short8;
typedef __attribute__((ext_vector_type(4))) float float4_;

typedef const __attribute__((address_space(1))) void* gas_t;
typedef __attribute__((address_space(3))) void* las_t;

// Async global->LDS, 16 B/lane. LDS dest is wave-uniform base + lane*16.
__device__ __forceinline__ void gl_lds16(const void* g, void* l) {
  __builtin_amdgcn_global_load_lds((gas_t)g, (las_t)l, 16, 0, 0);
}

__device__ __forceinline__ short f2b(float f) {
  union { __hip_bfloat16 h; short s; } u;
  u.h = __float2bfloat16(f);
  return u.s;
}
__device__ __forceinline__ float b2f(short s) {
  union { short s; __hip_bfloat16 h; } u;
  u.s = s;
  return __bfloat162float(u.h);
}
__device__ __forceinline__ short8 cvt8(float4_ lo, float4_ hi) {
  short8 r;
#pragma unroll
  for (int t = 0; t < 4; t++) { r[t] = f2b(lo[t]); r[t + 4] = f2b(hi[t]); }
  return r;
}

// fp32 -> bf16 elementwise, n multiple of 8.
__global__ __launch_bounds__(256) void f32_to_b16(
    const float* __restrict__ in, short* __restrict__ out, long n)
{
  const long i = ((long)blockIdx.x * 256 + threadIdx.x) * 8;
  if (i >= n) return;
  float4_ lo = *(const float4_*)&in[i];
  float4_ hi = *(const float4_*)&in[i + 4];
  *(short8*)&out[i] = cvt8(lo, hi);
}

// out[C][R] = bf16(in[R][C])^T; in fp32. 64x64 LDS tiles (stride 72: 16B-aligned).
__global__ __launch_bounds__(256) void transpose64(
    const float* __restrict__ in, short* __restrict__ out, int R, int C)
{
  __shared__ __align__(16) short T[64 * 72];
  const int tid = threadIdx.x;
  const int r0 = blockIdx.y * 64;
  const int c0 = blockIdx.x * 64;
  const int r  = tid >> 2;
  const int cp = (tid & 3) * 16;
#pragma unroll
  for (int g = 0; g < 4; g++) {
    float4_ v = *(const float4_*)&in[(long)(r0 + r) * C + c0 + cp + g * 4];
#pragma unroll
    for (int t = 0; t < 4; t++) T[(cp + g * 4 + t) * 72 + r] = f2b(v[t]);
  }
  __syncthreads();
  const int c  = tid >> 2;
  const int rp = (tid & 3) * 16;
  short8 w0 = *(const short8*)&T[c * 72 + rp];
  short8 w1 = *(const short8*)&T[c * 72 + rp + 8];
  *(short8*)&out[(long)(c0 + c) * R + r0 + rp] = w0;
  *(short8*)&out[(long)(c0 + c) * R + r0 + rp + 8] = w1;
}

// C[M,N] = A[M,K] @ B[N,K]^T (+ bias). A bf16 or fp32 (a_f32); B bf16.
// C bf16, or fp32 with fp32 bias when c_f32. 128x128 tile, 4 waves (2x2 of
// 64x64), BK=32, fp32 accum. bf16 operands staged via global_load_lds x16
// (m97 structure); fp32 A falls back to reg-staging + convert.
__global__ __launch_bounds__(256) void gemm_bt(
    const void* __restrict__ Av, int lda, int a_f32,
    const short* __restrict__ B,
    void* __restrict__ Cv, int ldc, int c_f32,
    int K, const float* __restrict__ bias)
{
  __shared__ __align__(16) short As[128 * 32];
  __shared__ __align__(16) short Bs[128 * 32];
  const int tid  = threadIdx.x;
  const int lane = tid & 63;
  const int w    = tid >> 6;
  const int quad = lane >> 4;
  const int l15  = lane & 15;
  const int wm   = (w >> 1) * 64;
  const int wn   = (w & 1) * 64;
  const int m0   = blockIdx.y * 128;
  const int n0   = blockIdx.x * 128;
  const int wbase = w * 512;        // wave-uniform LDS base (shorts)

  float4_ acc[4][4] = {};

  const int srow = tid >> 2;        // 0..63
  const int kp   = (tid & 3) * 8;   // k-part (elements)

  for (int k0 = 0; k0 < K; k0 += 32) {
    short8 a_lo, a_hi;
    if (a_f32) {
      const float* Af = (const float*)Av;
      float4_ l0 = *(const float4_*)&Af[(long)(m0 + srow) * lda + k0 + kp];
      float4_ l1 = *(const float4_*)&Af[(long)(m0 + srow) * lda + k0 + kp + 4];
      float4_ h0 = *(const float4_*)&Af[(long)(m0 + srow + 64) * lda + k0 + kp];
      float4_ h1 = *(const float4_*)&Af[(long)(m0 + srow + 64) * lda + k0 + kp + 4];
      a_lo = cvt8(l0, l1);
      a_hi = cvt8(h0, h1);
    }
    __syncthreads();  // previous iteration's LDS reads done
    if (a_f32) {
      *(short8*)&As[srow * 32 + kp]        = a_lo;
      *(short8*)&As[(srow + 64) * 32 + kp] = a_hi;
    } else {
      const short* Ab = (const short*)Av;
      gl_lds16(&Ab[(long)(m0 + srow) * lda + k0 + kp],      &As[wbase]);
      gl_lds16(&Ab[(long)(m0 + srow + 64) * lda + k0 + kp], &As[2048 + wbase]);
    }
    gl_lds16(&B[(long)(n0 + srow) * K + k0 + kp],      &Bs[wbase]);
    gl_lds16(&B[(long)(n0 + srow + 64) * K + k0 + kp], &Bs[2048 + wbase]);
    __syncthreads();  // compiler drains vmcnt+lgkmcnt before s_barrier
    short8 a[4], b[4];
#pragma unroll
    for (int i = 0; i < 4; i++)
      a[i] = *(const short8*)&As[(wm + i * 16 + l15) * 32 + quad * 8];
#pragma unroll
    for (int j = 0; j < 4; j++)
      b[j] = *(const short8*)&Bs[(wn + j * 16 + l15) * 32 + quad * 8];
#pragma unroll
    for (int i = 0; i < 4; i++)
#pragma unroll
      for (int j = 0; j < 4; j++)
        acc[i][j] = __builtin_amdgcn_mfma_f32_16x16x32_bf16(a[i], b[j], acc[i][j], 0, 0, 0);
  }

#pragma unroll
  for (int i = 0; i < 4; i++) {
    const int rm = m0 + wm + i * 16 + quad * 4;
#pragma unroll
    for (int j = 0; j < 4; j++) {
      const int cn = n0 + wn + j * 16 + l15;
      if (c_f32) {
        float* C = (float*)Cv;
        const float bv = bias ? bias[cn] : 0.0f;
#pragma unroll
        for (int r = 0; r < 4; r++)
          C[(long)(rm + r) * ldc + cn] = acc[i][j][r] + bv;
      } else {
        short* C = (short*)Cv;
#pragma unroll
        for (int r = 0; r < 4; r++)
          C[(long)(rm + r) * ldc + cn] = f2b(acc[i][j][r]);
      }
    }
  }
}

// One workgroup per 128-row block: Q,K,V = qkv[rows +0..128, {0,1024,2048}+cols]
// S = QK^T/32, causal-mask, softmax (+1e-6), O = P V, written in-place into the
// Q columns (all Q reads complete in phase 1; each block touches only its rows).
// Phase 1 stages Q/K via global_load_lds; phase 3 stages V transposed in LDS
// (coalesced loads; B-fragments become ds_read_b128 instead of scalar gathers).
__global__ __launch_bounds__(256) void attn_blockdiag(short* __restrict__ qkv)
{
  __shared__ __align__(16) short Qs[128 * 32];
  __shared__ __align__(16) short Ks[128 * 32];
  __shared__ __align__(16) short Ps[128 * 136];  // row stride 136 (272 B, 16B-aligned)
  __shared__ __align__(16) short Vt[64 * 136];   // V^T tile: Vt[d][k], d0..d0+64

  const int tid  = threadIdx.x;
  const int lane = tid & 63;
  const int w    = tid >> 6;
  const int quad = lane >> 4;
  const int l15  = lane & 15;
  const long base = (long)blockIdx.x * 128 * 3072;
  const int wbase = w * 512;        // wave-uniform LDS base (shorts)

  // ---- Phase 1: S = Q K^T. wave w owns rows 32w..32w+31 (full 128 cols in-wave).
  float4_ acc[2][8] = {};
  const int srow = tid >> 2;
  const int kp   = (tid & 3) * 8;
  const short* Qg = qkv + base;
  const short* Kg = qkv + base + 1024;

  for (int k0 = 0; k0 < 1024; k0 += 32) {
    __syncthreads();  // previous iteration's LDS reads done
    gl_lds16(&Qg[(long)srow * 3072 + k0 + kp],        &Qs[wbase]);
    gl_lds16(&Qg[(long)(srow + 64) * 3072 + k0 + kp], &Qs[2048 + wbase]);
    gl_lds16(&Kg[(long)srow * 3072 + k0 + kp],        &Ks[wbase]);
    gl_lds16(&Kg[(long)(srow + 64) * 3072 + k0 + kp], &Ks[2048 + wbase]);
    __syncthreads();
    short8 a0 = *(const short8*)&Qs[(w * 32 + l15) * 32 + quad * 8];
    short8 a1 = *(const short8*)&Qs[(w * 32 + 16 + l15) * 32 + quad * 8];
#pragma unroll
    for (int j = 0; j < 8; j++) {
      short8 b = *(const short8*)&Ks[(j * 16 + l15) * 32 + quad * 8];
      acc[0][j] = __builtin_amdgcn_mfma_f32_16x16x32_bf16(a0, b, acc[0][j], 0, 0, 0);
      acc[1][j] = __builtin_amdgcn_mfma_f32_16x16x32_bf16(a1, b, acc[1][j], 0, 0, 0);
    }
  }
  __syncthreads();

  // ---- Phase 2: mask + softmax, in registers + 16-lane shuffles.
  const float scale = 0.03125f;  // 1024^-0.5
#pragma unroll
  for (int i = 0; i < 2; i++) {
#pragma unroll
    for (int r = 0; r < 4; r++) {
      const int rowq = w * 32 + i * 16 + quad * 4 + r;
      float s[8];
      float mx = -3.0e38f;
#pragma unroll
      for (int j = 0; j < 8; j++) {
        const int col = j * 16 + l15;
        const float v = acc[i][j][r] * scale;
        s[j] = (col <= rowq) ? v : -3.0e38f;
        mx = fmaxf(mx, s[j]);
      }
      mx = fmaxf(mx, __shfl_xor(mx, 1));
      mx = fmaxf(mx, __shfl_xor(mx, 2));
      mx = fmaxf(mx, __shfl_xor(mx, 4));
      mx = fmaxf(mx, __shfl_xor(mx, 8));
      float p[8];
      float sum = 0.0f;
#pragma unroll
      for (int j = 0; j < 8; j++) {
        p[j] = (s[j] > -1.0e38f) ? __expf(s[j] - mx) : 0.0f;
        sum += p[j];
      }
      sum += __shfl_xor(sum, 1);
      sum += __shfl_xor(sum, 2);
      sum += __shfl_xor(sum, 4);
      sum += __shfl_xor(sum, 8);
      const float inv = 1.0f / (sum + 1e-6f);
#pragma unroll
      for (int j = 0; j < 8; j++)
        Ps[rowq * 136 + j * 16 + l15] = f2b(p[j] * inv);  // C-layout -> A-layout via LDS
    }
  }

  // ---- Phase 3: O = P V. A from Ps (b128); B from Vt (V staged transposed in LDS).
  const short* Vg = qkv + base + 2048;
  short* Op = qkv + base;  // in-place into Q columns
  const int kr = tid >> 1;          // 0..127: V row this thread stages
  const int dp = (tid & 1) * 32;    // d-part within the 64-wide tile

  for (int d0 = 0; d0 < 1024; d0 += 64) {
    __syncthreads();  // prev iteration's Vt reads (and phase-2 Ps writes) done
    // stage V[0:128][d0:d0+64] -> Vt[d][k], coalesced short8 loads
#pragma unroll
    for (int g = 0; g < 4; g++) {
      short8 v = *(const short8*)&Vg[(long)kr * 3072 + d0 + dp + g * 8];
#pragma unroll
      for (int t = 0; t < 8; t++)
        Vt[(dp + g * 8 + t) * 136 + kr] = v[t];
    }
    __syncthreads();

    float4_ o[2][4] = {};
#pragma unroll
    for (int kk = 0; kk < 4; kk++) {
      short8 a0 = *(const short8*)&Ps[(w * 32 + l15) * 136 + kk * 32 + quad * 8];
      short8 a1 = *(const short8*)&Ps[(w * 32 + 16 + l15) * 136 + kk * 32 + quad * 8];
      const int kb = kk * 32 + quad * 8;
#pragma unroll
      for (int j = 0; j < 4; j++) {
        short8 b = *(const short8*)&Vt[(j * 16 + l15) * 136 + kb];
        o[0][j] = __builtin_amdgcn_mfma_f32_16x16x32_bf16(a0, b, o[0][j], 0, 0, 0);
        o[1][j] = __builtin_amdgcn_mfma_f32_16x16x32_bf16(a1, b, o[1][j], 0, 0, 0);
      }
    }
#pragma unroll
    for (int i = 0; i < 2; i++)
#pragma unroll
      for (int j = 0; j < 4; j++)
#pragma unroll
        for (int r = 0; r < 4; r++) {
          const int rq = w * 32 + i * 16 + quad * 4 + r;
          const int d  = d0 + j * 16 + l15;
          Op[(long)rq * 3072 + d] = f2b(o[i][j][r]);
        }
  }
}

extern "C" void kernel_launch(void* const* d_in, const int* in_sizes, int n_in,
                              void* d_out, int out_size, void* d_ws, size_t ws_size,
                              hipStream_t stream) {
  // Inputs fp32 (R2 bf16-read -> NaN). OUTPUT fp32 (reference returns fp32;
  // R3==R4 bit-identical absmax proved compute correct, I/O dtype was the bug).
  const float* x    = (const float*)d_in[0];  // [4,4096,1024]
  const float* Wqkv = (const float*)d_in[1];  // [1024,3072]
  const float* Wout = (const float*)d_in[2];  // [1024,1024] (= [N][K] for @W_out^T)
  const float* bout = (const float*)d_in[3];  // [1024]
  float* out = (float*)d_out;                 // [4,4096,1024] fp32

  char* ws = (char*)d_ws;
  short* WqkvT = (short*)ws;                    // [3072][1024] bf16:  6,291,456 B
  short* Woutb = (short*)(ws + 6291456);        // [1024][1024] bf16:  2,097,152 B
  short* qkv   = (short*)(ws + 8388608);        // bf16, up to [16384][3072]
  short* xb    = (short*)(ws + 8388608 + (size_t)16384 * 3072 * 2);  // [16384][1024]

  transpose64<<<dim3(48, 16), 256, 0, stream>>>(Wqkv, WqkvT, 1024, 3072);
  f32_to_b16<<<512, 256, 0, stream>>>(Wout, Woutb, 1048576L);

  if (ws_size >= 8388608 + (size_t)16384 * 3072 * 2 + (size_t)16384 * 1024 * 2) {
    // Tier A (143 MB): pre-convert x to bf16, full-width pipeline.
    f32_to_b16<<<8192, 256, 0, stream>>>(x, xb, 16777216L);
    gemm_bt<<<dim3(24, 128), 256, 0, stream>>>(xb, 1024, 0, WqkvT,
                                               qkv, 3072, 0, 1024, nullptr);
    attn_blockdiag<<<dim3(128), 256, 0, stream>>>(qkv);
    gemm_bt<<<dim3(8, 128), 256, 0, stream>>>(qkv, 3072, 0, Woutb,
                                              out, 1024, 1, 1024, bout);
  } else if (ws_size >= 8388608 + (size_t)16384 * 3072 * 2) {
    // Tier B (109 MB): full-width, gemm1 converts x fp32 -> bf16 while staging.
    gemm_bt<<<dim3(24, 128), 256, 0, stream>>>(x, 1024, 1, WqkvT,
                                               qkv, 3072, 0, 1024, nullptr);
    attn_blockdiag<<<dim3(128), 256, 0, stream>>>(qkv);
    gemm_bt<<<dim3(8, 128), 256, 0, stream>>>(qkv, 3072, 0, Woutb,
                                              out, 1024, 1, 1024, bout);
  } else {
    // Tier C (34 MB): per-batch chunks of 4096 rows.
    for (int c = 0; c < 4; c++) {
      const float* xc = x + (long)c * 4096 * 1024;
      float* outc = out + (long)c * 4096 * 1024;
      gemm_bt<<<dim3(24, 32), 256, 0, stream>>>(xc, 1024, 1, WqkvT,
                                                qkv, 3072, 0, 1024, nullptr);
      attn_blockdiag<<<dim3(32), 256, 0, stream>>>(qkv);
      gemm_bt<<<dim3(8, 32), 256, 0, stream>>>(qkv, 3072, 0, Woutb,
                                               outc, 1024, 1, 1024, bout);
    }
  }
}

// Round 3
// 376.604 us; speedup vs baseline: 1.0237x; 1.0089x over previous
//
#include <hip/hip_runtime.h>
#include <hip/hip_bf16.h>

typedef __attribute__((ext_vector_type(8))) short short8;
typedef __attribute__((ext_vector_type(4))) float float4_;

typedef const __attribute__((address_space(1))) void* gas_t;
typedef __attribute__((address_space(3))) void* las_t;

// Async global->LDS, 16 B/lane. LDS dest is wave-uniform base + lane*16.
__device__ __forceinline__ void gl_lds16(const void* g, void* l) {
  __builtin_amdgcn_global_load_lds((gas_t)g, (las_t)l, 16, 0, 0);
}

__device__ __forceinline__ short f2b(float f) {
  union { __hip_bfloat16 h; short s; } u;
  u.h = __float2bfloat16(f);
  return u.s;
}
__device__ __forceinline__ float b2f(short s) {
  union { short s; __hip_bfloat16 h; } u;
  u.s = s;
  return __bfloat162float(u.h);
}
__device__ __forceinline__ short8 cvt8(float4_ lo, float4_ hi) {
  short8 r;
#pragma unroll
  for (int t = 0; t < 4; t++) { r[t] = f2b(lo[t]); r[t + 4] = f2b(hi[t]); }
  return r;
}

// fp32 -> bf16 elementwise, n multiple of 8.
__global__ __launch_bounds__(256) void f32_to_b16(
    const float* __restrict__ in, short* __restrict__ out, long n)
{
  const long i = ((long)blockIdx.x * 256 + threadIdx.x) * 8;
  if (i >= n) return;
  float4_ lo = *(const float4_*)&in[i];
  float4_ hi = *(const float4_*)&in[i + 4];
  *(short8*)&out[i] = cvt8(lo, hi);
}

// out[C][R] = bf16(in[R][C])^T; in fp32. 64x64 LDS tiles (stride 72: 16B-aligned).
__global__ __launch_bounds__(256) void transpose64(
    const float* __restrict__ in, short* __restrict__ out, int R, int C)
{
  __shared__ __align__(16) short T[64 * 72];
  const int tid = threadIdx.x;
  const int r0 = blockIdx.y * 64;
  const int c0 = blockIdx.x * 64;
  const int r  = tid >> 2;
  const int cp = (tid & 3) * 16;
#pragma unroll
  for (int g = 0; g < 4; g++) {
    float4_ v = *(const float4_*)&in[(long)(r0 + r) * C + c0 + cp + g * 4];
#pragma unroll
    for (int t = 0; t < 4; t++) T[(cp + g * 4 + t) * 72 + r] = f2b(v[t]);
  }
  __syncthreads();
  const int c  = tid >> 2;
  const int rp = (tid & 3) * 16;
  short8 w0 = *(const short8*)&T[c * 72 + rp];
  short8 w1 = *(const short8*)&T[c * 72 + rp + 8];
  *(short8*)&out[(long)(c0 + c) * R + r0 + rp] = w0;
  *(short8*)&out[(long)(c0 + c) * R + r0 + rp + 8] = w1;
}

// C[M,N] = A[M,K] @ B[N,K]^T (+ bias). A bf16 or fp32 (a_f32); B bf16.
// C bf16, or fp32 with fp32 bias when c_f32. 128x128 tile, 4 waves (2x2 of
// 64x64), BK=32, fp32 accum. bf16 operands staged via global_load_lds x16.
// Epilogue: C tile transposed through LDS scratch (XOR-swizzled) -> coalesced
// short8/float4 stores instead of 64 scalar stores per thread.
__global__ __launch_bounds__(256) void gemm_bt(
    const void* __restrict__ Av, int lda, int a_f32,
    const short* __restrict__ B,
    void* __restrict__ Cv, int ldc, int c_f32,
    int K, const float* __restrict__ bias)
{
  __shared__ __align__(16) short smem[2 * 128 * 32];  // As | Bs; epilogue scratch
  const int tid  = threadIdx.x;
  const int lane = tid & 63;
  const int w    = tid >> 6;
  const int quad = lane >> 4;
  const int l15  = lane & 15;
  const int wm   = (w >> 1) * 64;
  const int wn   = (w & 1) * 64;
  const int m0   = blockIdx.y * 128;
  const int n0   = blockIdx.x * 128;
  const int wbase = w * 512;        // wave-uniform LDS base (shorts)

  float4_ acc[4][4] = {};

  const int srow = tid >> 2;        // 0..63
  const int kp   = (tid & 3) * 8;   // k-part (elements)

  for (int k0 = 0; k0 < K; k0 += 32) {
    short8 a_lo, a_hi;
    if (a_f32) {
      const float* Af = (const float*)Av;
      float4_ l0 = *(const float4_*)&Af[(long)(m0 + srow) * lda + k0 + kp];
      float4_ l1 = *(const float4_*)&Af[(long)(m0 + srow) * lda + k0 + kp + 4];
      float4_ h0 = *(const float4_*)&Af[(long)(m0 + srow + 64) * lda + k0 + kp];
      float4_ h1 = *(const float4_*)&Af[(long)(m0 + srow + 64) * lda + k0 + kp + 4];
      a_lo = cvt8(l0, l1);
      a_hi = cvt8(h0, h1);
    }
    __syncthreads();  // previous iteration's LDS reads done
    if (a_f32) {
      *(short8*)&smem[srow * 32 + kp]        = a_lo;
      *(short8*)&smem[(srow + 64) * 32 + kp] = a_hi;
    } else {
      const short* Ab = (const short*)Av;
      gl_lds16(&Ab[(long)(m0 + srow) * lda + k0 + kp],      &smem[wbase]);
      gl_lds16(&Ab[(long)(m0 + srow + 64) * lda + k0 + kp], &smem[2048 + wbase]);
    }
    gl_lds16(&B[(long)(n0 + srow) * K + k0 + kp],      &smem[4096 + wbase]);
    gl_lds16(&B[(long)(n0 + srow + 64) * K + k0 + kp], &smem[6144 + wbase]);
    __syncthreads();  // drains vmcnt+lgkmcnt before s_barrier
    short8 a[4], b[4];
#pragma unroll
    for (int i = 0; i < 4; i++)
      a[i] = *(const short8*)&smem[(wm + i * 16 + l15) * 32 + quad * 8];
#pragma unroll
    for (int j = 0; j < 4; j++)
      b[j] = *(const short8*)&smem[4096 + (wn + j * 16 + l15) * 32 + quad * 8];
#pragma unroll
    for (int i = 0; i < 4; i++)
#pragma unroll
      for (int j = 0; j < 4; j++)
        acc[i][j] = __builtin_amdgcn_mfma_f32_16x16x32_bf16(a[i], b[j], acc[i][j], 0, 0, 0);
  }

  // Epilogue: per i (16-row strip pair), transpose acc through LDS, store wide.
  const int gidx = w >> 1;  // which 64-row half this wave owns
  for (int i = 0; i < 4; i++) {
    __syncthreads();  // prior scratch/LDS reads done
    if (c_f32) {
      float* scr = (float*)smem;   // [32][128] fp32 = 16 KB exactly
#pragma unroll
      for (int j = 0; j < 4; j++) {
        const int col = wn + j * 16 + l15;
        const float bv = bias ? bias[n0 + col] : 0.0f;
#pragma unroll
        for (int r = 0; r < 4; r++) {
          const int row = gidx * 16 + quad * 4 + r;
          scr[row * 128 + (col ^ ((row & 7) << 4))] = acc[i][j][r] + bv;
        }
      }
    } else {
#pragma unroll
      for (int j = 0; j < 4; j++) {
        const int col = wn + j * 16 + l15;
#pragma unroll
        for (int r = 0; r < 4; r++) {
          const int row = gidx * 16 + quad * 4 + r;
          smem[row * 128 + (col ^ ((row & 7) << 4))] = f2b(acc[i][j][r]);
        }
      }
    }
    __syncthreads();
    const int rs   = tid >> 3;          // 0..31
    const int colp = (tid & 7) * 16;    // 0..112
    const int cs   = colp ^ ((rs & 7) << 4);
    const long row_g = m0 + (rs >> 4) * 64 + i * 16 + (rs & 15);
    if (c_f32) {
      float* C = (float*)Cv;
      const float* scr = (const float*)smem;
#pragma unroll
      for (int q = 0; q < 4; q++) {
        float4_ v = *(const float4_*)&scr[rs * 128 + cs + q * 4];
        *(float4_*)&C[row_g * ldc + n0 + colp + q * 4] = v;
      }
    } else {
      short* C = (short*)Cv;
      short8 v0 = *(const short8*)&smem[rs * 128 + cs];
      short8 v1 = *(const short8*)&smem[rs * 128 + cs + 8];
      *(short8*)&C[row_g * ldc + n0 + colp]     = v0;
      *(short8*)&C[row_g * ldc + n0 + colp + 8] = v1;
    }
  }
}

// Block-diagonal causal attention, causal-split: each 128-row tile is handled
// by TWO workgroups. Lower half (rows 0-63) needs keys 0-63 (NJ=4); upper half
// (rows 64-127) needs keys 0-127 (NJ=8). Grid = 2 * n_tiles -> all 256 CUs
// busy. O written in-place into Q columns (each WG reads only its own Q rows,
// all in phase 1; K/V columns never written).
template<int NJ>  // NJ = NK/16
__device__ __forceinline__ void attn_body(short* __restrict__ qkv, int tile,
                                          short* smem)
{
  constexpr int NK    = NJ * 16;          // 64 or 128
  constexpr int STR   = NK + 8;           // 72 or 136 (16B-aligned rows)
  constexpr int QROW0 = (NJ == 8) ? 64 : 0;
  short* Qs = smem;                       // [64*32]
  short* Ks = smem + 2048;                // [NK*32]
  short* Ps = Ks + NK * 32;               // [64*STR]
  short* Vt = Ps + 64 * STR;              // [64*STR]  (Vt[d][k])
  short* Ot = Vt + 64 * STR;              // [64*72]

  const int tid  = threadIdx.x;
  const int lane = tid & 63;
  const int w    = tid >> 6;
  const int quad = lane >> 4;
  const int l15  = lane & 15;
  const long base = (long)tile * 128 * 3072;
  const int wbase = w * 512;

  const short* Qg = qkv + base + (long)QROW0 * 3072;
  const short* Kg = qkv + base + 1024;
  const short* Vg = qkv + base + 2048;

  // ---- Phase 1: S = Q K^T. Wave w owns Q rows w*16..w*16+15 (all NK cols).
  float4_ acc[NJ] = {};
  const int srow = tid >> 2;        // 0..63
  const int kp   = (tid & 3) * 8;

  for (int k0 = 0; k0 < 1024; k0 += 32) {
    __syncthreads();  // previous iteration's LDS reads done
    gl_lds16(&Qg[(long)srow * 3072 + k0 + kp], &Qs[wbase]);
    gl_lds16(&Kg[(long)srow * 3072 + k0 + kp], &Ks[wbase]);
    if (NJ == 8)
      gl_lds16(&Kg[(long)(srow + 64) * 3072 + k0 + kp], &Ks[2048 + wbase]);
    __syncthreads();
    short8 a = *(const short8*)&Qs[(w * 16 + l15) * 32 + quad * 8];
#pragma unroll
    for (int j = 0; j < NJ; j++) {
      short8 b = *(const short8*)&Ks[(j * 16 + l15) * 32 + quad * 8];
      acc[j] = __builtin_amdgcn_mfma_f32_16x16x32_bf16(a, b, acc[j], 0, 0, 0);
    }
  }

  // ---- Phase 2: mask + softmax in registers + 16-lane shuffles.
  const float scale = 0.03125f;  // 1024^-0.5
#pragma unroll
  for (int r = 0; r < 4; r++) {
    const int rowq = w * 16 + quad * 4 + r;   // local row 0..63
    float s[NJ];
    float mx = -3.0e38f;
#pragma unroll
    for (int j = 0; j < NJ; j++) {
      const int col = j * 16 + l15;
      const float v = acc[j][r] * scale;
      s[j] = (col <= QROW0 + rowq) ? v : -3.0e38f;
      mx = fmaxf(mx, s[j]);
    }
    mx = fmaxf(mx, __shfl_xor(mx, 1));
    mx = fmaxf(mx, __shfl_xor(mx, 2));
    mx = fmaxf(mx, __shfl_xor(mx, 4));
    mx = fmaxf(mx, __shfl_xor(mx, 8));
    float p[NJ];
    float sum = 0.0f;
#pragma unroll
    for (int j = 0; j < NJ; j++) {
      p[j] = (s[j] > -1.0e38f) ? __expf(s[j] - mx) : 0.0f;
      sum += p[j];
    }
    sum += __shfl_xor(sum, 1);
    sum += __shfl_xor(sum, 2);
    sum += __shfl_xor(sum, 4);
    sum += __shfl_xor(sum, 8);
    const float inv = 1.0f / (sum + 1e-6f);
#pragma unroll
    for (int j = 0; j < NJ; j++)
      Ps[rowq * STR + j * 16 + l15] = f2b(p[j] * inv);
  }

  // ---- Phase 3: O = P V, V staged transposed in LDS, O staged through LDS
  // for coalesced short8 stores.
  short* Op = qkv + base + (long)QROW0 * 3072;
  for (int d0 = 0; d0 < 1024; d0 += 64) {
    __syncthreads();  // prev iter's Vt/Ot reads (and phase-2 Ps writes) done
    if (NJ == 8) {
      const int kr = tid >> 1, dp = (tid & 1) * 32;
#pragma unroll
      for (int gg = 0; gg < 4; gg++) {
        short8 v = *(const short8*)&Vg[(long)kr * 3072 + d0 + dp + gg * 8];
#pragma unroll
        for (int t = 0; t < 8; t++) Vt[(dp + gg * 8 + t) * STR + kr] = v[t];
      }
    } else {
      const int kr = tid >> 2, dp = (tid & 3) * 16;
#pragma unroll
      for (int gg = 0; gg < 2; gg++) {
        short8 v = *(const short8*)&Vg[(long)kr * 3072 + d0 + dp + gg * 8];
#pragma unroll
        for (int t = 0; t < 8; t++) Vt[(dp + gg * 8 + t) * STR + kr] = v[t];
      }
    }
    __syncthreads();
    float4_ o[4] = {};
#pragma unroll
    for (int kk = 0; kk < NK / 32; kk++) {
      short8 a = *(const short8*)&Ps[(w * 16 + l15) * STR + kk * 32 + quad * 8];
#pragma unroll
      for (int j = 0; j < 4; j++) {
        short8 b = *(const short8*)&Vt[(j * 16 + l15) * STR + kk * 32 + quad * 8];
        o[j] = __builtin_amdgcn_mfma_f32_16x16x32_bf16(a, b, o[j], 0, 0, 0);
      }
    }
#pragma unroll
    for (int j = 0; j < 4; j++)
#pragma unroll
      for (int r = 0; r < 4; r++)
        Ot[(w * 16 + quad * 4 + r) * 72 + j * 16 + l15] = f2b(o[j][r]);
    __syncthreads();
    const int orow = tid >> 2, ocp = (tid & 3) * 16;
    short8 v0 = *(const short8*)&Ot[orow * 72 + ocp];
    short8 v1 = *(const short8*)&Ot[orow * 72 + ocp + 8];
    *(short8*)&Op[(long)orow * 3072 + d0 + ocp]     = v0;
    *(short8*)&Op[(long)orow * 3072 + d0 + ocp + 8] = v1;
  }
}

__global__ __launch_bounds__(256) void attn_blockdiag(short* __restrict__ qkv)
{
  __shared__ __align__(16) short smem[28160];  // worst case (NJ=8): 55 KB
  const int tile = blockIdx.x >> 1;
  if (blockIdx.x & 1) attn_body<8>(qkv, tile, smem);
  else                attn_body<4>(qkv, tile, smem);
}

extern "C" void kernel_launch(void* const* d_in, const int* in_sizes, int n_in,
                              void* d_out, int out_size, void* d_ws, size_t ws_size,
                              hipStream_t stream) {
  // Inputs fp32; OUTPUT fp32 (reference returns fp32).
  const float* x    = (const float*)d_in[0];  // [4,4096,1024]
  const float* Wqkv = (const float*)d_in[1];  // [1024,3072]
  const float* Wout = (const float*)d_in[2];  // [1024,1024] (= [N][K] for @W_out^T)
  const float* bout = (const float*)d_in[3];  // [1024]
  float* out = (float*)d_out;                 // [4,4096,1024] fp32

  char* ws = (char*)d_ws;
  short* WqkvT = (short*)ws;                    // [3072][1024] bf16:  6,291,456 B
  short* Woutb = (short*)(ws + 6291456);        // [1024][1024] bf16:  2,097,152 B
  short* qkv   = (short*)(ws + 8388608);        // bf16, up to [16384][3072]
  short* xb    = (short*)(ws + 8388608 + (size_t)16384 * 3072 * 2);  // [16384][1024]

  transpose64<<<dim3(48, 16), 256, 0, stream>>>(Wqkv, WqkvT, 1024, 3072);
  f32_to_b16<<<512, 256, 0, stream>>>(Wout, Woutb, 1048576L);

  if (ws_size >= 8388608 + (size_t)16384 * 3072 * 2 + (size_t)16384 * 1024 * 2) {
    // Tier A (143 MB): pre-convert x to bf16, full-width pipeline.
    f32_to_b16<<<8192, 256, 0, stream>>>(x, xb, 16777216L);
    gemm_bt<<<dim3(24, 128), 256, 0, stream>>>(xb, 1024, 0, WqkvT,
                                               qkv, 3072, 0, 1024, nullptr);
    attn_blockdiag<<<dim3(256), 256, 0, stream>>>(qkv);
    gemm_bt<<<dim3(8, 128), 256, 0, stream>>>(qkv, 3072, 0, Woutb,
                                              out, 1024, 1, 1024, bout);
  } else if (ws_size >= 8388608 + (size_t)16384 * 3072 * 2) {
    // Tier B (109 MB): full-width, gemm1 converts x fp32 -> bf16 while staging.
    gemm_bt<<<dim3(24, 128), 256, 0, stream>>>(x, 1024, 1, WqkvT,
                                               qkv, 3072, 0, 1024, nullptr);
    attn_blockdiag<<<dim3(256), 256, 0, stream>>>(qkv);
    gemm_bt<<<dim3(8, 128), 256, 0, stream>>>(qkv, 3072, 0, Woutb,
                                              out, 1024, 1, 1024, bout);
  } else {
    // Tier C (34 MB): per-batch chunks of 4096 rows.
    for (int c = 0; c < 4; c++) {
      const float* xc = x + (long)c * 4096 * 1024;
      float* outc = out + (long)c * 4096 * 1024;
      gemm_bt<<<dim3(24, 32), 256, 0, stream>>>(xc, 1024, 1, WqkvT,
                                                qkv, 3072, 0, 1024, nullptr);
      attn_blockdiag<<<dim3(64), 256, 0, stream>>>(qkv);
      gemm_bt<<<dim3(8, 32), 256, 0, stream>>>(qkv, 3072, 0, Woutb,
                                               outc, 1024, 1, 1024, bout);
    }
  }
}

// Round 4
// 345.886 us; speedup vs baseline: 1.1146x; 1.0888x over previous
//
#include <hip/hip_runtime.h>
#include <hip/hip_bf16.h>

typedef __attribute__((ext_vector_type(8))) short short8;
typedef __attribute__((ext_vector_type(4))) float float4_;

typedef const __attribute__((address_space(1))) void* gas_t;
typedef __attribute__((address_space(3))) void* las_t;

// Async global->LDS, 16 B/lane. LDS dest is wave-uniform base + lane*16.
__device__ __forceinline__ void gl_lds16(const void* g, void* l) {
  __builtin_amdgcn_global_load_lds((gas_t)g, (las_t)l, 16, 0, 0);
}

__device__ __forceinline__ short f2b(float f) {
  union { __hip_bfloat16 h; short s; } u;
  u.h = __float2bfloat16(f);
  return u.s;
}
__device__ __forceinline__ short8 cvt8(float4_ lo, float4_ hi) {
  short8 r;
#pragma unroll
  for (int t = 0; t < 4; t++) { r[t] = f2b(lo[t]); r[t + 4] = f2b(hi[t]); }
  return r;
}

// Fused prep: [0,768) transpose Wqkv -> WqkvT (bf16, [3072][1024]);
// [768,1280) convert Wout -> bf16; [1280,...) convert x -> bf16 (if has_x).
// One launch instead of three (launch-overhead hypothesis test).
__global__ __launch_bounds__(256) void prep(
    const float* __restrict__ Wqkv, short* __restrict__ WqkvT,
    const float* __restrict__ Wout, short* __restrict__ Woutb,
    const float* __restrict__ x, short* __restrict__ xb, int has_x)
{
  __shared__ __align__(16) short T[64 * 72];
  const int b   = blockIdx.x;
  const int tid = threadIdx.x;
  if (b < 768) {
    // transpose64 body: in [1024][3072] fp32 -> out [3072][1024] bf16
    const int R = 1024, C = 3072;
    const int r0 = (b / 48) * 64;
    const int c0 = (b % 48) * 64;
    const int r  = tid >> 2;
    const int cp = (tid & 3) * 16;
#pragma unroll
    for (int g = 0; g < 4; g++) {
      float4_ v = *(const float4_*)&Wqkv[(long)(r0 + r) * C + c0 + cp + g * 4];
#pragma unroll
      for (int t = 0; t < 4; t++) T[(cp + g * 4 + t) * 72 + r] = f2b(v[t]);
    }
    __syncthreads();
    const int c  = tid >> 2;
    const int rp = (tid & 3) * 16;
    short8 w0 = *(const short8*)&T[c * 72 + rp];
    short8 w1 = *(const short8*)&T[c * 72 + rp + 8];
    *(short8*)&WqkvT[(long)(c0 + c) * R + r0 + rp] = w0;
    *(short8*)&WqkvT[(long)(c0 + c) * R + r0 + rp + 8] = w1;
  } else if (b < 1280) {
    const long i = ((long)(b - 768) * 256 + tid) * 8;
    float4_ lo = *(const float4_*)&Wout[i];
    float4_ hi = *(const float4_*)&Wout[i + 4];
    *(short8*)&Woutb[i] = cvt8(lo, hi);
  } else if (has_x) {
    const long i = ((long)(b - 1280) * 256 + tid) * 8;
    float4_ lo = *(const float4_*)&x[i];
    float4_ hi = *(const float4_*)&x[i + 4];
    *(short8*)&xb[i] = cvt8(lo, hi);
  }
}

// C[M,N] = A[M,K] @ B[N,K]^T (+ bias). A bf16 or fp32 (a_f32); B bf16.
// 128x128 tile, 4 waves (2x2 of 64x64), BK=64 (16 barrier-drains at K=1024),
// fp32 accum. LDS rows are 128 B with 16B-chunk XOR swizzle (chunk ^= row&7):
// global_load_lds keeps a LINEAR dest while the SOURCE k-offset is
// pre-swizzled (rule: both-sides-or-neither); ds_read uses the same XOR ->
// 2 lanes/bank (free) instead of 8-way conflicts.
// XCD-aware bijective block swizzle: each XCD gets contiguous m-strips.
__global__ __launch_bounds__(256) void gemm_bt(
    const void* __restrict__ Av, int lda, int a_f32,
    const short* __restrict__ B,
    void* __restrict__ Cv, int ldc, int c_f32,
    int K, const float* __restrict__ bias)
{
  __shared__ __align__(16) short As[128 * 64];  // 16 KB (also epilogue scratch)
  __shared__ __align__(16) short Bs[128 * 64];  // 16 KB
  const int tid  = threadIdx.x;
  const int lane = tid & 63;
  const int w    = tid >> 6;
  const int quad = lane >> 4;
  const int l15  = lane & 15;
  const int wm   = (w >> 1) * 64;
  const int wn   = (w & 1) * 64;

  // XCD swizzle (grids here are always %8==0; guard anyway)
  const int nx  = gridDim.x;
  const int nwg = nx * gridDim.y;
  int wid = blockIdx.y * nx + blockIdx.x;
  if ((nwg & 7) == 0) wid = (wid & 7) * (nwg >> 3) + (wid >> 3);
  const int m0 = (wid / nx) * 128;
  const int n0 = (wid % nx) * 128;

  float4_ acc[4][4] = {};

  // bf16 staging geometry: 4 calls/operand; call g covers rows g*32..g*32+31.
  const int srow = tid >> 3;                       // 0..31
  const int sk   = tid & 7;                        // 16B chunk in row
  const int kswz = ((sk ^ (srow & 7)) * 8);        // pre-swizzled src k-elems
  const int wbase = w * 512;                       // shorts: wave base in a call
  // fp32 staging geometry (reg-staged): row = tid>>1, half = (tid&1)*32 k.
  const int frow = tid >> 1;
  const int fh   = tid & 1;
  const int swzc = quad ^ (l15 & 7);               // note: (row&7)==l15&7 on reads

  for (int k0 = 0; k0 < K; k0 += 64) {
    short8 fs[4];
    if (a_f32) {
      const float* Af = (const float*)Av;
#pragma unroll
      for (int g = 0; g < 2; g++) {
        float4_ v0 = *(const float4_*)&Af[(long)(m0 + frow) * lda + k0 + fh * 32 + g * 16];
        float4_ v1 = *(const float4_*)&Af[(long)(m0 + frow) * lda + k0 + fh * 32 + g * 16 + 4];
        float4_ v2 = *(const float4_*)&Af[(long)(m0 + frow) * lda + k0 + fh * 32 + g * 16 + 8];
        float4_ v3 = *(const float4_*)&Af[(long)(m0 + frow) * lda + k0 + fh * 32 + g * 16 + 12];
        fs[g * 2]     = cvt8(v0, v1);
        fs[g * 2 + 1] = cvt8(v2, v3);
      }
    }
    __syncthreads();  // previous iteration's LDS reads done
    if (a_f32) {
#pragma unroll
      for (int g = 0; g < 4; g++) {
        const int c_log = fh * 4 + g;
        *(short8*)&As[frow * 64 + ((c_log ^ (frow & 7)) * 8)] = fs[g];
      }
    } else {
      const short* Ab = (const short*)Av;
#pragma unroll
      for (int g = 0; g < 4; g++)
        gl_lds16(&Ab[(long)(m0 + g * 32 + srow) * lda + k0 + kswz],
                 &As[g * 2048 + wbase]);
    }
#pragma unroll
    for (int g = 0; g < 4; g++)
      gl_lds16(&B[(long)(n0 + g * 32 + srow) * K + k0 + kswz],
               &Bs[g * 2048 + wbase]);
    __syncthreads();  // drains vmcnt+lgkmcnt before s_barrier
#pragma unroll
    for (int kk = 0; kk < 2; kk++) {
      short8 a[4], b[4];
      const int ch = (kk * 4) ^ swzc;  // (kk*4+quad) ^ (l15&7): quad folded in swzc
#pragma unroll
      for (int i = 0; i < 4; i++)
        a[i] = *(const short8*)&As[(wm + i * 16 + l15) * 64 + ((kk * 4 + quad) ^ (l15 & 7)) * 8];
#pragma unroll
      for (int j = 0; j < 4; j++)
        b[j] = *(const short8*)&Bs[(wn + j * 16 + l15) * 64 + ((kk * 4 + quad) ^ (l15 & 7)) * 8];
      (void)ch;
#pragma unroll
      for (int i = 0; i < 4; i++)
#pragma unroll
        for (int j = 0; j < 4; j++)
          acc[i][j] = __builtin_amdgcn_mfma_f32_16x16x32_bf16(a[i], b[j], acc[i][j], 0, 0, 0);
    }
  }

  // Epilogue: per i (16-row strip pair), transpose acc through LDS (As as
  // scratch, XOR-swizzled), store coalesced short8/float4.
  const int gidx = w >> 1;
  for (int i = 0; i < 4; i++) {
    __syncthreads();  // prior scratch/LDS reads done
    if (c_f32) {
      float* scr = (float*)As;   // [32][128] fp32 = 16 KB exactly
#pragma unroll
      for (int j = 0; j < 4; j++) {
        const int col = wn + j * 16 + l15;
        const float bv = bias ? bias[n0 + col] : 0.0f;
#pragma unroll
        for (int r = 0; r < 4; r++) {
          const int row = gidx * 16 + quad * 4 + r;
          scr[row * 128 + (col ^ ((row & 7) << 4))] = acc[i][j][r] + bv;
        }
      }
    } else {
#pragma unroll
      for (int j = 0; j < 4; j++) {
        const int col = wn + j * 16 + l15;
#pragma unroll
        for (int r = 0; r < 4; r++) {
          const int row = gidx * 16 + quad * 4 + r;
          As[row * 128 + (col ^ ((row & 7) << 4))] = f2b(acc[i][j][r]);
        }
      }
    }
    __syncthreads();
    const int rs   = tid >> 3;          // 0..31
    const int colp = (tid & 7) * 16;    // 0..112
    const int cs   = colp ^ ((rs & 7) << 4);
    const long row_g = m0 + (rs >> 4) * 64 + i * 16 + (rs & 15);
    if (c_f32) {
      float* C = (float*)Cv;
      const float* scr = (const float*)As;
#pragma unroll
      for (int q = 0; q < 4; q++) {
        float4_ v = *(const float4_*)&scr[rs * 128 + cs + q * 4];
        *(float4_*)&C[row_g * ldc + n0 + colp + q * 4] = v;
      }
    } else {
      short* C = (short*)Cv;
      short8 v0 = *(const short8*)&As[rs * 128 + cs];
      short8 v1 = *(const short8*)&As[rs * 128 + cs + 8];
      *(short8*)&C[row_g * ldc + n0 + colp]     = v0;
      *(short8*)&C[row_g * ldc + n0 + colp + 8] = v1;
    }
  }
}

// Block-diagonal causal attention, causal-split: each 128-row tile is handled
// by TWO workgroups. Lower half (rows 0-63) needs keys 0-63 (NJ=4); upper half
// (rows 64-127) needs keys 0-127 (NJ=8). Grid = 2 * n_tiles. O written
// in-place into Q columns. (Verified R3 code, unchanged.)
template<int NJ>  // NJ = NK/16
__device__ __forceinline__ void attn_body(short* __restrict__ qkv, int tile,
                                          short* smem)
{
  constexpr int NK    = NJ * 16;          // 64 or 128
  constexpr int STR   = NK + 8;           // 72 or 136 (16B-aligned rows)
  constexpr int QROW0 = (NJ == 8) ? 64 : 0;
  short* Qs = smem;                       // [64*32]
  short* Ks = smem + 2048;                // [NK*32]
  short* Ps = Ks + NK * 32;               // [64*STR]
  short* Vt = Ps + 64 * STR;              // [64*STR]  (Vt[d][k])
  short* Ot = Vt + 64 * STR;              // [64*72]

  const int tid  = threadIdx.x;
  const int lane = tid & 63;
  const int w    = tid >> 6;
  const int quad = lane >> 4;
  const int l15  = lane & 15;
  const long base = (long)tile * 128 * 3072;
  const int wbase = w * 512;

  const short* Qg = qkv + base + (long)QROW0 * 3072;
  const short* Kg = qkv + base + 1024;
  const short* Vg = qkv + base + 2048;

  // ---- Phase 1: S = Q K^T. Wave w owns Q rows w*16..w*16+15 (all NK cols).
  float4_ acc[NJ] = {};
  const int srow = tid >> 2;        // 0..63
  const int kp   = (tid & 3) * 8;

  for (int k0 = 0; k0 < 1024; k0 += 32) {
    __syncthreads();  // previous iteration's LDS reads done
    gl_lds16(&Qg[(long)srow * 3072 + k0 + kp], &Qs[wbase]);
    gl_lds16(&Kg[(long)srow * 3072 + k0 + kp], &Ks[wbase]);
    if (NJ == 8)
      gl_lds16(&Kg[(long)(srow + 64) * 3072 + k0 + kp], &Ks[2048 + wbase]);
    __syncthreads();
    short8 a = *(const short8*)&Qs[(w * 16 + l15) * 32 + quad * 8];
#pragma unroll
    for (int j = 0; j < NJ; j++) {
      short8 b = *(const short8*)&Ks[(j * 16 + l15) * 32 + quad * 8];
      acc[j] = __builtin_amdgcn_mfma_f32_16x16x32_bf16(a, b, acc[j], 0, 0, 0);
    }
  }

  // ---- Phase 2: mask + softmax in registers + 16-lane shuffles.
  const float scale = 0.03125f;  // 1024^-0.5
#pragma unroll
  for (int r = 0; r < 4; r++) {
    const int rowq = w * 16 + quad * 4 + r;   // local row 0..63
    float s[NJ];
    float mx = -3.0e38f;
#pragma unroll
    for (int j = 0; j < NJ; j++) {
      const int col = j * 16 + l15;
      const float v = acc[j][r] * scale;
      s[j] = (col <= QROW0 + rowq) ? v : -3.0e38f;
      mx = fmaxf(mx, s[j]);
    }
    mx = fmaxf(mx, __shfl_xor(mx, 1));
    mx = fmaxf(mx, __shfl_xor(mx, 2));
    mx = fmaxf(mx, __shfl_xor(mx, 4));
    mx = fmaxf(mx, __shfl_xor(mx, 8));
    float p[NJ];
    float sum = 0.0f;
#pragma unroll
    for (int j = 0; j < NJ; j++) {
      p[j] = (s[j] > -1.0e38f) ? __expf(s[j] - mx) : 0.0f;
      sum += p[j];
    }
    sum += __shfl_xor(sum, 1);
    sum += __shfl_xor(sum, 2);
    sum += __shfl_xor(sum, 4);
    sum += __shfl_xor(sum, 8);
    const float inv = 1.0f / (sum + 1e-6f);
#pragma unroll
    for (int j = 0; j < NJ; j++)
      Ps[rowq * STR + j * 16 + l15] = f2b(p[j] * inv);
  }

  // ---- Phase 3: O = P V, V staged transposed in LDS, O staged through LDS
  // for coalesced short8 stores.
  short* Op = qkv + base + (long)QROW0 * 3072;
  for (int d0 = 0; d0 < 1024; d0 += 64) {
    __syncthreads();  // prev iter's Vt/Ot reads (and phase-2 Ps writes) done
    if (NJ == 8) {
      const int kr = tid >> 1, dp = (tid & 1) * 32;
#pragma unroll
      for (int gg = 0; gg < 4; gg++) {
        short8 v = *(const short8*)&Vg[(long)kr * 3072 + d0 + dp + gg * 8];
#pragma unroll
        for (int t = 0; t < 8; t++) Vt[(dp + gg * 8 + t) * STR + kr] = v[t];
      }
    } else {
      const int kr = tid >> 2, dp = (tid & 3) * 16;
#pragma unroll
      for (int gg = 0; gg < 2; gg++) {
        short8 v = *(const short8*)&Vg[(long)kr * 3072 + d0 + dp + gg * 8];
#pragma unroll
        for (int t = 0; t < 8; t++) Vt[(dp + gg * 8 + t) * STR + kr] = v[t];
      }
    }
    __syncthreads();
    float4_ o[4] = {};
#pragma unroll
    for (int kk = 0; kk < NK / 32; kk++) {
      short8 a = *(const short8*)&Ps[(w * 16 + l15) * STR + kk * 32 + quad * 8];
#pragma unroll
      for (int j = 0; j < 4; j++) {
        short8 b = *(const short8*)&Vt[(j * 16 + l15) * STR + kk * 32 + quad * 8];
        o[j] = __builtin_amdgcn_mfma_f32_16x16x32_bf16(a, b, o[j], 0, 0, 0);
      }
    }
#pragma unroll
    for (int j = 0; j < 4; j++)
#pragma unroll
      for (int r = 0; r < 4; r++)
        Ot[(w * 16 + quad * 4 + r) * 72 + j * 16 + l15] = f2b(o[j][r]);
    __syncthreads();
    const int orow = tid >> 2, ocp = (tid & 3) * 16;
    short8 v0 = *(const short8*)&Ot[orow * 72 + ocp];
    short8 v1 = *(const short8*)&Ot[orow * 72 + ocp + 8];
    *(short8*)&Op[(long)orow * 3072 + d0 + ocp]     = v0;
    *(short8*)&Op[(long)orow * 3072 + d0 + ocp + 8] = v1;
  }
}

__global__ __launch_bounds__(256) void attn_blockdiag(short* __restrict__ qkv)
{
  __shared__ __align__(16) short smem[28160];  // worst case (NJ=8): 55 KB
  const int tile = blockIdx.x >> 1;
  if (blockIdx.x & 1) attn_body<8>(qkv, tile, smem);
  else                attn_body<4>(qkv, tile, smem);
}

extern "C" void kernel_launch(void* const* d_in, const int* in_sizes, int n_in,
                              void* d_out, int out_size, void* d_ws, size_t ws_size,
                              hipStream_t stream) {
  // Inputs fp32; OUTPUT fp32 (reference returns fp32).
  const float* x    = (const float*)d_in[0];  // [4,4096,1024]
  const float* Wqkv = (const float*)d_in[1];  // [1024,3072]
  const float* Wout = (const float*)d_in[2];  // [1024,1024] (= [N][K] for @W_out^T)
  const float* bout = (const float*)d_in[3];  // [1024]
  float* out = (float*)d_out;                 // [4,4096,1024] fp32

  char* ws = (char*)d_ws;
  short* WqkvT = (short*)ws;                    // [3072][1024] bf16:  6,291,456 B
  short* Woutb = (short*)(ws + 6291456);        // [1024][1024] bf16:  2,097,152 B
  short* qkv   = (short*)(ws + 8388608);        // bf16, up to [16384][3072]
  short* xb    = (short*)(ws + 8388608 + (size_t)16384 * 3072 * 2);  // [16384][1024]

  if (ws_size >= 8388608 + (size_t)16384 * 3072 * 2 + (size_t)16384 * 1024 * 2) {
    // Tier A (143 MB): one fused prep (transpose + 2 converts), full pipeline.
    prep<<<9472, 256, 0, stream>>>(Wqkv, WqkvT, Wout, Woutb, x, xb, 1);
    gemm_bt<<<dim3(24, 128), 256, 0, stream>>>(xb, 1024, 0, WqkvT,
                                               qkv, 3072, 0, 1024, nullptr);
    attn_blockdiag<<<dim3(256), 256, 0, stream>>>(qkv);
    gemm_bt<<<dim3(8, 128), 256, 0, stream>>>(qkv, 3072, 0, Woutb,
                                              out, 1024, 1, 1024, bout);
  } else if (ws_size >= 8388608 + (size_t)16384 * 3072 * 2) {
    // Tier B (109 MB): gemm1 converts x fp32 -> bf16 while staging.
    prep<<<1280, 256, 0, stream>>>(Wqkv, WqkvT, Wout, Woutb, nullptr, nullptr, 0);
    gemm_bt<<<dim3(24, 128), 256, 0, stream>>>(x, 1024, 1, WqkvT,
                                               qkv, 3072, 0, 1024, nullptr);
    attn_blockdiag<<<dim3(256), 256, 0, stream>>>(qkv);
    gemm_bt<<<dim3(8, 128), 256, 0, stream>>>(qkv, 3072, 0, Woutb,
                                              out, 1024, 1, 1024, bout);
  } else {
    // Tier C (34 MB): per-batch chunks of 4096 rows.
    prep<<<1280, 256, 0, stream>>>(Wqkv, WqkvT, Wout, Woutb, nullptr, nullptr, 0);
    for (int c = 0; c < 4; c++) {
      const float* xc = x + (long)c * 4096 * 1024;
      float* outc = out + (long)c * 4096 * 1024;
      gemm_bt<<<dim3(24, 32), 256, 0, stream>>>(xc, 1024, 1, WqkvT,
                                                qkv, 3072, 0, 1024, nullptr);
      attn_blockdiag<<<dim3(64), 256, 0, stream>>>(qkv);
      gemm_bt<<<dim3(8, 32), 256, 0, stream>>>(qkv, 3072, 0, Woutb,
                                               outc, 1024, 1, 1024, bout);
    }
  }
}

// Round 5
// 328.531 us; speedup vs baseline: 1.1735x; 1.0528x over previous
//
#include <hip/hip_runtime.h>
#include <hip/hip_bf16.h>

typedef __attribute__((ext_vector_type(8))) short short8;
typedef __attribute__((ext_vector_type(4))) float float4_;

typedef const __attribute__((address_space(1))) void* gas_t;
typedef __attribute__((address_space(3))) void* las_t;

// Async global->LDS, 16 B/lane. LDS dest is wave-uniform base + lane*16.
__device__ __forceinline__ void gl_lds16(const void* g, void* l) {
  __builtin_amdgcn_global_load_lds((gas_t)g, (las_t)l, 16, 0, 0);
}

__device__ __forceinline__ short f2b(float f) {
  union { __hip_bfloat16 h; short s; } u;
  u.h = __float2bfloat16(f);
  return u.s;
}
__device__ __forceinline__ short8 cvt8(float4_ lo, float4_ hi) {
  short8 r;
#pragma unroll
  for (int t = 0; t < 4; t++) { r[t] = f2b(lo[t]); r[t + 4] = f2b(hi[t]); }
  return r;
}

// Fused prep: [0,768) transpose Wqkv -> WqkvT (bf16, [3072][1024]);
// [768,1280) convert Wout -> bf16; [1280,...) convert x -> bf16 (if has_x).
__global__ __launch_bounds__(256) void prep(
    const float* __restrict__ Wqkv, short* __restrict__ WqkvT,
    const float* __restrict__ Wout, short* __restrict__ Woutb,
    const float* __restrict__ x, short* __restrict__ xb, int has_x)
{
  __shared__ __align__(16) short T[64 * 72];
  const int b   = blockIdx.x;
  const int tid = threadIdx.x;
  if (b < 768) {
    const int R = 1024, C = 3072;
    const int r0 = (b / 48) * 64;
    const int c0 = (b % 48) * 64;
    const int r  = tid >> 2;
    const int cp = (tid & 3) * 16;
#pragma unroll
    for (int g = 0; g < 4; g++) {
      float4_ v = *(const float4_*)&Wqkv[(long)(r0 + r) * C + c0 + cp + g * 4];
#pragma unroll
      for (int t = 0; t < 4; t++) T[(cp + g * 4 + t) * 72 + r] = f2b(v[t]);
    }
    __syncthreads();
    const int c  = tid >> 2;
    const int rp = (tid & 3) * 16;
    short8 w0 = *(const short8*)&T[c * 72 + rp];
    short8 w1 = *(const short8*)&T[c * 72 + rp + 8];
    *(short8*)&WqkvT[(long)(c0 + c) * R + r0 + rp] = w0;
    *(short8*)&WqkvT[(long)(c0 + c) * R + r0 + rp + 8] = w1;
  } else if (b < 1280) {
    const long i = ((long)(b - 768) * 256 + tid) * 8;
    float4_ lo = *(const float4_*)&Wout[i];
    float4_ hi = *(const float4_*)&Wout[i + 4];
    *(short8*)&Woutb[i] = cvt8(lo, hi);
  } else if (has_x) {
    const long i = ((long)(b - 1280) * 256 + tid) * 8;
    float4_ lo = *(const float4_*)&x[i];
    float4_ hi = *(const float4_*)&x[i + 4];
    *(short8*)&xb[i] = cvt8(lo, hi);
  }
}

// C[M,N] = A[M,K] @ B[N,K]^T (+ bias). 128x128 tile, 4 waves, BK=64,
// chunk-XOR LDS swizzle (both-sides), XCD-bijective block swizzle.
// (Verified R4 code, unchanged.)
__global__ __launch_bounds__(256) void gemm_bt(
    const void* __restrict__ Av, int lda, int a_f32,
    const short* __restrict__ B,
    void* __restrict__ Cv, int ldc, int c_f32,
    int K, const float* __restrict__ bias)
{
  __shared__ __align__(16) short As[128 * 64];  // 16 KB (also epilogue scratch)
  __shared__ __align__(16) short Bs[128 * 64];  // 16 KB
  const int tid  = threadIdx.x;
  const int lane = tid & 63;
  const int w    = tid >> 6;
  const int quad = lane >> 4;
  const int l15  = lane & 15;
  const int wm   = (w >> 1) * 64;
  const int wn   = (w & 1) * 64;

  const int nx  = gridDim.x;
  const int nwg = nx * gridDim.y;
  int wid = blockIdx.y * nx + blockIdx.x;
  if ((nwg & 7) == 0) wid = (wid & 7) * (nwg >> 3) + (wid >> 3);
  const int m0 = (wid / nx) * 128;
  const int n0 = (wid % nx) * 128;

  float4_ acc[4][4] = {};

  const int srow = tid >> 3;                       // 0..31
  const int sk   = tid & 7;                        // 16B chunk in row
  const int kswz = ((sk ^ (srow & 7)) * 8);        // pre-swizzled src k-elems
  const int wbase = w * 512;
  const int frow = tid >> 1;
  const int fh   = tid & 1;

  for (int k0 = 0; k0 < K; k0 += 64) {
    short8 fs[4];
    if (a_f32) {
      const float* Af = (const float*)Av;
#pragma unroll
      for (int g = 0; g < 2; g++) {
        float4_ v0 = *(const float4_*)&Af[(long)(m0 + frow) * lda + k0 + fh * 32 + g * 16];
        float4_ v1 = *(const float4_*)&Af[(long)(m0 + frow) * lda + k0 + fh * 32 + g * 16 + 4];
        float4_ v2 = *(const float4_*)&Af[(long)(m0 + frow) * lda + k0 + fh * 32 + g * 16 + 8];
        float4_ v3 = *(const float4_*)&Af[(long)(m0 + frow) * lda + k0 + fh * 32 + g * 16 + 12];
        fs[g * 2]     = cvt8(v0, v1);
        fs[g * 2 + 1] = cvt8(v2, v3);
      }
    }
    __syncthreads();
    if (a_f32) {
#pragma unroll
      for (int g = 0; g < 4; g++) {
        const int c_log = fh * 4 + g;
        *(short8*)&As[frow * 64 + ((c_log ^ (frow & 7)) * 8)] = fs[g];
      }
    } else {
      const short* Ab = (const short*)Av;
#pragma unroll
      for (int g = 0; g < 4; g++)
        gl_lds16(&Ab[(long)(m0 + g * 32 + srow) * lda + k0 + kswz],
                 &As[g * 2048 + wbase]);
    }
#pragma unroll
    for (int g = 0; g < 4; g++)
      gl_lds16(&B[(long)(n0 + g * 32 + srow) * K + k0 + kswz],
               &Bs[g * 2048 + wbase]);
    __syncthreads();
#pragma unroll
    for (int kk = 0; kk < 2; kk++) {
      short8 a[4], b[4];
#pragma unroll
      for (int i = 0; i < 4; i++)
        a[i] = *(const short8*)&As[(wm + i * 16 + l15) * 64 + ((kk * 4 + quad) ^ (l15 & 7)) * 8];
#pragma unroll
      for (int j = 0; j < 4; j++)
        b[j] = *(const short8*)&Bs[(wn + j * 16 + l15) * 64 + ((kk * 4 + quad) ^ (l15 & 7)) * 8];
#pragma unroll
      for (int i = 0; i < 4; i++)
#pragma unroll
        for (int j = 0; j < 4; j++)
          acc[i][j] = __builtin_amdgcn_mfma_f32_16x16x32_bf16(a[i], b[j], acc[i][j], 0, 0, 0);
    }
  }

  const int gidx = w >> 1;
  for (int i = 0; i < 4; i++) {
    __syncthreads();
    if (c_f32) {
      float* scr = (float*)As;
#pragma unroll
      for (int j = 0; j < 4; j++) {
        const int col = wn + j * 16 + l15;
        const float bv = bias ? bias[n0 + col] : 0.0f;
#pragma unroll
        for (int r = 0; r < 4; r++) {
          const int row = gidx * 16 + quad * 4 + r;
          scr[row * 128 + (col ^ ((row & 7) << 4))] = acc[i][j][r] + bv;
        }
      }
    } else {
#pragma unroll
      for (int j = 0; j < 4; j++) {
        const int col = wn + j * 16 + l15;
#pragma unroll
        for (int r = 0; r < 4; r++) {
          const int row = gidx * 16 + quad * 4 + r;
          As[row * 128 + (col ^ ((row & 7) << 4))] = f2b(acc[i][j][r]);
        }
      }
    }
    __syncthreads();
    const int rs   = tid >> 3;
    const int colp = (tid & 7) * 16;
    const int cs   = colp ^ ((rs & 7) << 4);
    const long row_g = m0 + (rs >> 4) * 64 + i * 16 + (rs & 15);
    if (c_f32) {
      float* C = (float*)Cv;
      const float* scr = (const float*)As;
#pragma unroll
      for (int q = 0; q < 4; q++) {
        float4_ v = *(const float4_*)&scr[rs * 128 + cs + q * 4];
        *(float4_*)&C[row_g * ldc + n0 + colp + q * 4] = v;
      }
    } else {
      short* C = (short*)Cv;
      short8 v0 = *(const short8*)&As[rs * 128 + cs];
      short8 v1 = *(const short8*)&As[rs * 128 + cs + 8];
      *(short8*)&C[row_g * ldc + n0 + colp]     = v0;
      *(short8*)&C[row_g * ldc + n0 + colp + 8] = v1;
    }
  }
}

// Block-diagonal causal attention. Causal split (2 WGs per 128-row tile) as
// before, but now 512 threads = 8 waves = 2 waves/SIMD per WG.
// Wave-group g = tid>>8 splits work WITHOUT extra HBM traffic:
//   phase 1: split-K (g handles k0 = g*64 + i*128, 8 iters, K-step 64 with
//            R4-verified chunk-XOR LDS swizzle); partial S summed via LDS.
//   phase 3: split-D (g handles d0 = g*64 + i*128, 8 iters); P shared in LDS.
// LDS regions overlaid per phase; every barrier is block-uniform (both groups
// execute equal iteration counts).
template<int NJ>  // NJ = NK/16
__device__ __forceinline__ void attn_body(short* __restrict__ qkv, int tile,
                                          short* smem)
{
  constexpr int NK    = NJ * 16;          // 64 or 128
  constexpr int QROW0 = (NJ == 8) ? 64 : 0;
  constexpr int KCALLS = NK / 32;

  short* Ps = smem;                       // [64*136] bf16 P (phase 2 -> 3)
  short* U  = smem + 8704;                // overlaid union region (26624 shorts)

  const int tid  = threadIdx.x;
  const int t8   = tid & 255;             // thread id within group
  const int g    = tid >> 8;              // wave-group 0/1
  const int wl   = (tid >> 6) & 3;        // wave within group
  const int lane = tid & 63;
  const int quad = lane >> 4;
  const int l15  = lane & 15;
  const long base = (long)tile * 128 * 3072;

  const short* Qg = qkv + base + (long)QROW0 * 3072;
  const short* Kg = qkv + base + 1024;
  const short* Vg = qkv + base + 2048;

  // ---- Phase 1: S = Q K^T, split-K across groups. K-step 64, XOR swizzle.
  short* Qs = U + g * 4096;               // [64][64]
  short* Ks = U + 8192 + g * 8192;        // [NK][64]
  const int srow8 = t8 >> 3;              // 0..31
  const int sk    = t8 & 7;
  const int kswz  = (sk ^ (srow8 & 7)) * 8;
  const int wb    = wl * 512;             // wave base within a 2048-short call

  float4_ acc[NJ] = {};

  for (int i = 0; i < 8; i++) {
    const int k0 = g * 64 + i * 128;
    __syncthreads();  // previous iteration's LDS reads done (both groups)
#pragma unroll
    for (int c = 0; c < 2; c++)
      gl_lds16(&Qg[(long)(c * 32 + srow8) * 3072 + k0 + kswz], &Qs[c * 2048 + wb]);
#pragma unroll
    for (int c = 0; c < KCALLS; c++)
      gl_lds16(&Kg[(long)(c * 32 + srow8) * 3072 + k0 + kswz], &Ks[c * 2048 + wb]);
    __syncthreads();  // drains vmcnt before barrier
#pragma unroll
    for (int kk = 0; kk < 2; kk++) {
      const int ch = ((kk * 4 + quad) ^ (l15 & 7)) * 8;
      short8 a = *(const short8*)&Qs[(wl * 16 + l15) * 64 + ch];
#pragma unroll
      for (int j = 0; j < NJ; j++) {
        short8 b = *(const short8*)&Ks[(j * 16 + l15) * 64 + ch];
        acc[j] = __builtin_amdgcn_mfma_f32_16x16x32_bf16(a, b, acc[j], 0, 0, 0);
      }
    }
  }
  __syncthreads();  // all phase-1 LDS reads done before region reuse

  // ---- Phase 2: sum partials (via fp32 LDS scratch), mask + softmax (group 0).
  float* Sscr = (float*)U;                // [64][132] fp32
  if (g == 1) {
#pragma unroll
    for (int r = 0; r < 4; r++) {
      const int rowq = wl * 16 + quad * 4 + r;
#pragma unroll
      for (int j = 0; j < NJ; j++)
        Sscr[rowq * 132 + j * 16 + l15] = acc[j][r];
    }
  }
  __syncthreads();
  if (g == 0) {
    const float scale = 0.03125f;  // 1024^-0.5
#pragma unroll
    for (int r = 0; r < 4; r++) {
      const int rowq = wl * 16 + quad * 4 + r;
      float s[NJ];
      float mx = -3.0e38f;
#pragma unroll
      for (int j = 0; j < NJ; j++) {
        const int col = j * 16 + l15;
        const float v = (acc[j][r] + Sscr[rowq * 132 + col]) * scale;
        s[j] = (col <= QROW0 + rowq) ? v : -3.0e38f;
        mx = fmaxf(mx, s[j]);
      }
      mx = fmaxf(mx, __shfl_xor(mx, 1));
      mx = fmaxf(mx, __shfl_xor(mx, 2));
      mx = fmaxf(mx, __shfl_xor(mx, 4));
      mx = fmaxf(mx, __shfl_xor(mx, 8));
      float p[NJ];
      float sum = 0.0f;
#pragma unroll
      for (int j = 0; j < NJ; j++) {
        p[j] = (s[j] > -1.0e38f) ? __expf(s[j] - mx) : 0.0f;
        sum += p[j];
      }
      sum += __shfl_xor(sum, 1);
      sum += __shfl_xor(sum, 2);
      sum += __shfl_xor(sum, 4);
      sum += __shfl_xor(sum, 8);
      const float inv = 1.0f / (sum + 1e-6f);
#pragma unroll
      for (int j = 0; j < NJ; j++)
        Ps[rowq * 136 + j * 16 + l15] = f2b(p[j] * inv);
    }
  }
  __syncthreads();  // P visible to both groups; Sscr dead

  // ---- Phase 3: O = P V, split-D across groups. V staged transposed per
  // group; O staged through LDS for coalesced short8 stores.
  short* Vt = U + g * 8704;               // [64][136]  (Vt[d][k])
  short* Ot = U + 17408 + g * 4608;       // [64][72]
  short* Op = qkv + base + (long)QROW0 * 3072;

  for (int i = 0; i < 8; i++) {
    const int d0 = g * 64 + i * 128;
    __syncthreads();  // prev iteration's Vt/Ot reads done (both groups)
    if (NJ == 8) {
      const int kr = t8 >> 1, dp = (t8 & 1) * 32;
#pragma unroll
      for (int gg = 0; gg < 4; gg++) {
        short8 v = *(const short8*)&Vg[(long)kr * 3072 + d0 + dp + gg * 8];
#pragma unroll
        for (int t = 0; t < 8; t++) Vt[(dp + gg * 8 + t) * 136 + kr] = v[t];
      }
    } else {
      const int kr = t8 >> 2, dp = (t8 & 3) * 16;
#pragma unroll
      for (int gg = 0; gg < 2; gg++) {
        short8 v = *(const short8*)&Vg[(long)kr * 3072 + d0 + dp + gg * 8];
#pragma unroll
        for (int t = 0; t < 8; t++) Vt[(dp + gg * 8 + t) * 136 + kr] = v[t];
      }
    }
    __syncthreads();
    float4_ o[4] = {};
#pragma unroll
    for (int kk = 0; kk < NK / 32; kk++) {
      short8 a = *(const short8*)&Ps[(wl * 16 + l15) * 136 + kk * 32 + quad * 8];
#pragma unroll
      for (int j = 0; j < 4; j++) {
        short8 b = *(const short8*)&Vt[(j * 16 + l15) * 136 + kk * 32 + quad * 8];
        o[j] = __builtin_amdgcn_mfma_f32_16x16x32_bf16(a, b, o[j], 0, 0, 0);
      }
    }
#pragma unroll
    for (int j = 0; j < 4; j++)
#pragma unroll
      for (int r = 0; r < 4; r++)
        Ot[(wl * 16 + quad * 4 + r) * 72 + j * 16 + l15] = f2b(o[j][r]);
    __syncthreads();
    const int orow = t8 >> 2, ocp = (t8 & 3) * 16;
    short8 v0 = *(const short8*)&Ot[orow * 72 + ocp];
    short8 v1 = *(const short8*)&Ot[orow * 72 + ocp + 8];
    *(short8*)&Op[(long)orow * 3072 + d0 + ocp]     = v0;
    *(short8*)&Op[(long)orow * 3072 + d0 + ocp + 8] = v1;
  }
}

__global__ __launch_bounds__(512) void attn_blockdiag(short* __restrict__ qkv)
{
  // Ps (8704) + union region (26624) = 35328 shorts = 70.7 KB
  __shared__ __align__(16) short smem[35328];
  const int tile = blockIdx.x >> 1;
  if (blockIdx.x & 1) attn_body<8>(qkv, tile, smem);
  else                attn_body<4>(qkv, tile, smem);
}

extern "C" void kernel_launch(void* const* d_in, const int* in_sizes, int n_in,
                              void* d_out, int out_size, void* d_ws, size_t ws_size,
                              hipStream_t stream) {
  // Inputs fp32; OUTPUT fp32 (reference returns fp32).
  const float* x    = (const float*)d_in[0];  // [4,4096,1024]
  const float* Wqkv = (const float*)d_in[1];  // [1024,3072]
  const float* Wout = (const float*)d_in[2];  // [1024,1024] (= [N][K] for @W_out^T)
  const float* bout = (const float*)d_in[3];  // [1024]
  float* out = (float*)d_out;                 // [4,4096,1024] fp32

  char* ws = (char*)d_ws;
  short* WqkvT = (short*)ws;                    // [3072][1024] bf16:  6,291,456 B
  short* Woutb = (short*)(ws + 6291456);        // [1024][1024] bf16:  2,097,152 B
  short* qkv   = (short*)(ws + 8388608);        // bf16, up to [16384][3072]
  short* xb    = (short*)(ws + 8388608 + (size_t)16384 * 3072 * 2);  // [16384][1024]

  if (ws_size >= 8388608 + (size_t)16384 * 3072 * 2 + (size_t)16384 * 1024 * 2) {
    // Tier A (143 MB): one fused prep (transpose + 2 converts), full pipeline.
    prep<<<9472, 256, 0, stream>>>(Wqkv, WqkvT, Wout, Woutb, x, xb, 1);
    gemm_bt<<<dim3(24, 128), 256, 0, stream>>>(xb, 1024, 0, WqkvT,
                                               qkv, 3072, 0, 1024, nullptr);
    attn_blockdiag<<<dim3(256), 512, 0, stream>>>(qkv);
    gemm_bt<<<dim3(8, 128), 256, 0, stream>>>(qkv, 3072, 0, Woutb,
                                              out, 1024, 1, 1024, bout);
  } else if (ws_size >= 8388608 + (size_t)16384 * 3072 * 2) {
    // Tier B (109 MB): gemm1 converts x fp32 -> bf16 while staging.
    prep<<<1280, 256, 0, stream>>>(Wqkv, WqkvT, Wout, Woutb, nullptr, nullptr, 0);
    gemm_bt<<<dim3(24, 128), 256, 0, stream>>>(x, 1024, 1, WqkvT,
                                               qkv, 3072, 0, 1024, nullptr);
    attn_blockdiag<<<dim3(256), 512, 0, stream>>>(qkv);
    gemm_bt<<<dim3(8, 128), 256, 0, stream>>>(qkv, 3072, 0, Woutb,
                                              out, 1024, 1, 1024, bout);
  } else {
    // Tier C (34 MB): per-batch chunks of 4096 rows.
    prep<<<1280, 256, 0, stream>>>(Wqkv, WqkvT, Wout, Woutb, nullptr, nullptr, 0);
    for (int c = 0; c < 4; c++) {
      const float* xc = x + (long)c * 4096 * 1024;
      float* outc = out + (long)c * 4096 * 1024;
      gemm_bt<<<dim3(24, 32), 256, 0, stream>>>(xc, 1024, 1, WqkvT,
                                                qkv, 3072, 0, 1024, nullptr);
      attn_blockdiag<<<dim3(64), 512, 0, stream>>>(qkv);
      gemm_bt<<<dim3(8, 32), 256, 0, stream>>>(qkv, 3072, 0, Woutb,
                                               outc, 1024, 1, 1024, bout);
    }
  }
}